// Round 3
// baseline (73.004 us; speedup 1.0000x reference)
//
#include <hip/hip_runtime.h>
#include <hip/hip_bf16.h>

// Paged attention decode, GQA G=4, fp32. Flash-decoding split-K.
// B=16, H=32, KVH=8, D=128, MAX_CTX=4096.
// 16 lanes per token (lane owns 8 contiguous dims); each lane-group
// processes 2 tokens per iteration with the next 2 prefetched (8 KB in
// flight per wave); 4 waves per block; PART=256 tokens per block.

namespace {
constexpr int B_ = 16;
constexpr int H_ = 32;
constexpr int KVH_ = 8;
constexpr int D_ = 128;
constexpr int G_ = H_ / KVH_;            // 4
constexpr int MAX_CTX_ = 4096;
constexpr int PART_ = 256;
constexpr int NPART_ = MAX_CTX_ / PART_; // 16
constexpr float SCALE_ = 0.088388347648318447f;  // 1/sqrt(128)
// ws per (b,kvh,part): O[G][D], m[G], l[G]
constexpr int PSTRIDE_ = G_ * D_ + 2 * G_;       // 520 floats
}

__global__ __launch_bounds__(256) void pa_partial(
    const float* __restrict__ q,        // [B][H][D]
    const float* __restrict__ kc,       // [NUM_SLOTS][KVH][D]
    const float* __restrict__ vc,       // [NUM_SLOTS][KVH][D]
    const int* __restrict__ slots,      // [B][MAX_CTX]
    const int* __restrict__ ctx_lens,   // [B]
    float* __restrict__ ws)
{
  const int part = blockIdx.x;
  const int kvh  = blockIdx.y;
  const int b    = blockIdx.z;
  const int ctx  = ctx_lens[b];
  const int t0   = part * PART_;
  if (t0 >= ctx) return;                 // uniform early-exit
  const int t1 = min(t0 + PART_, ctx);

  const int tid  = threadIdx.x;
  const int wid  = tid >> 6;             // 0..3
  const int lane = tid & 63;
  const int grp  = lane >> 4;            // 0..3 lane-group in wave
  const int sub  = lane & 15;            // owns dims [8*sub, 8*sub+8)

  // Q fragments, pre-scaled by 1/sqrt(D)
  float4 qa[G_], qb[G_];
#pragma unroll
  for (int g = 0; g < G_; ++g) {
    const float* qp = q + ((size_t)b * H_ + (size_t)(kvh * G_ + g)) * D_ + 8 * sub;
    qa[g] = *(const float4*)qp;
    qb[g] = *(const float4*)(qp + 4);
    qa[g].x *= SCALE_; qa[g].y *= SCALE_; qa[g].z *= SCALE_; qa[g].w *= SCALE_;
    qb[g].x *= SCALE_; qb[g].y *= SCALE_; qb[g].z *= SCALE_; qb[g].w *= SCALE_;
  }

  float m[G_], l[G_];
  float4 aa[G_], ab[G_];
#pragma unroll
  for (int g = 0; g < G_; ++g) {
    m[g] = -INFINITY;
    l[g] = 0.f;
    aa[g] = make_float4(0.f, 0.f, 0.f, 0.f);
    ab[g] = make_float4(0.f, 0.f, 0.f, 0.f);
  }

  const int* sp = slots + (size_t)b * MAX_CTX_;
  const int tmax = t1 - 1;
  const int lead = wid * 8 + grp;        // wave's group token offset in 32-chunk

  // slots for current iter (A = lead, B = lead+4) and next iter
  int sA0 = sp[min(t0 + lead,      tmax)];
  int sB0 = sp[min(t0 + lead + 4,  tmax)];
  int sA1 = sp[min(t0 + 32 + lead,     tmax)];
  int sB1 = sp[min(t0 + 32 + lead + 4, tmax)];

  const int doff = 8 * sub;
  size_t offA = ((size_t)sA0 * KVH_ + kvh) * D_ + doff;
  size_t offB = ((size_t)sB0 * KVH_ + kvh) * D_ + doff;
  float4 kA0 = *(const float4*)(kc + offA);
  float4 kA1 = *(const float4*)(kc + offA + 4);
  float4 vA0 = *(const float4*)(vc + offA);
  float4 vA1 = *(const float4*)(vc + offA + 4);
  float4 kB0 = *(const float4*)(kc + offB);
  float4 kB1 = *(const float4*)(kc + offB + 4);
  float4 vB0 = *(const float4*)(vc + offB);
  float4 vB1 = *(const float4*)(vc + offB + 4);

  for (int base = t0; base < t1; base += 32) {
    // slots two iterations ahead
    const int sA2 = sp[min(base + 64 + lead,     tmax)];
    const int sB2 = sp[min(base + 64 + lead + 4, tmax)];
    // prefetch K/V one iteration ahead
    const size_t nA = ((size_t)sA1 * KVH_ + kvh) * D_ + doff;
    const size_t nB = ((size_t)sB1 * KVH_ + kvh) * D_ + doff;
    const float4 nkA0 = *(const float4*)(kc + nA);
    const float4 nkA1 = *(const float4*)(kc + nA + 4);
    const float4 nvA0 = *(const float4*)(vc + nA);
    const float4 nvA1 = *(const float4*)(vc + nA + 4);
    const float4 nkB0 = *(const float4*)(kc + nB);
    const float4 nkB1 = *(const float4*)(kc + nB + 4);
    const float4 nvB0 = *(const float4*)(vc + nB);
    const float4 nvB1 = *(const float4*)(vc + nB + 4);

    // ---- token A ----
    if (base + lead < t1) {
      float s[G_];
#pragma unroll
      for (int g = 0; g < G_; ++g) {
        s[g] = qa[g].x * kA0.x + qa[g].y * kA0.y + qa[g].z * kA0.z + qa[g].w * kA0.w
             + qb[g].x * kA1.x + qb[g].y * kA1.y + qb[g].z * kA1.z + qb[g].w * kA1.w;
      }
#pragma unroll
      for (int g = 0; g < G_; ++g) {
#pragma unroll
        for (int o = 1; o < 16; o <<= 1) s[g] += __shfl_xor(s[g], o, 64);
      }
      const bool need = (s[0] > m[0] + 8.f) | (s[1] > m[1] + 8.f) |
                        (s[2] > m[2] + 8.f) | (s[3] > m[3] + 8.f);
      if (need) {
#pragma unroll
        for (int g = 0; g < G_; ++g) {
          const float mn = fmaxf(m[g], s[g]);
          const float c = __expf(m[g] - mn);
          m[g] = mn; l[g] *= c;
          aa[g].x *= c; aa[g].y *= c; aa[g].z *= c; aa[g].w *= c;
          ab[g].x *= c; ab[g].y *= c; ab[g].z *= c; ab[g].w *= c;
        }
      }
#pragma unroll
      for (int g = 0; g < G_; ++g) {
        const float p = __expf(s[g] - m[g]);
        l[g] += p;
        aa[g].x += p * vA0.x; aa[g].y += p * vA0.y;
        aa[g].z += p * vA0.z; aa[g].w += p * vA0.w;
        ab[g].x += p * vA1.x; ab[g].y += p * vA1.y;
        ab[g].z += p * vA1.z; ab[g].w += p * vA1.w;
      }
    }
    // ---- token B ----
    if (base + lead + 4 < t1) {
      float s[G_];
#pragma unroll
      for (int g = 0; g < G_; ++g) {
        s[g] = qa[g].x * kB0.x + qa[g].y * kB0.y + qa[g].z * kB0.z + qa[g].w * kB0.w
             + qb[g].x * kB1.x + qb[g].y * kB1.y + qb[g].z * kB1.z + qb[g].w * kB1.w;
      }
#pragma unroll
      for (int g = 0; g < G_; ++g) {
#pragma unroll
        for (int o = 1; o < 16; o <<= 1) s[g] += __shfl_xor(s[g], o, 64);
      }
      const bool need = (s[0] > m[0] + 8.f) | (s[1] > m[1] + 8.f) |
                        (s[2] > m[2] + 8.f) | (s[3] > m[3] + 8.f);
      if (need) {
#pragma unroll
        for (int g = 0; g < G_; ++g) {
          const float mn = fmaxf(m[g], s[g]);
          const float c = __expf(m[g] - mn);
          m[g] = mn; l[g] *= c;
          aa[g].x *= c; aa[g].y *= c; aa[g].z *= c; aa[g].w *= c;
          ab[g].x *= c; ab[g].y *= c; ab[g].z *= c; ab[g].w *= c;
        }
      }
#pragma unroll
      for (int g = 0; g < G_; ++g) {
        const float p = __expf(s[g] - m[g]);
        l[g] += p;
        aa[g].x += p * vB0.x; aa[g].y += p * vB0.y;
        aa[g].z += p * vB0.z; aa[g].w += p * vB0.w;
        ab[g].x += p * vB1.x; ab[g].y += p * vB1.y;
        ab[g].z += p * vB1.z; ab[g].w += p * vB1.w;
      }
    }

    kA0 = nkA0; kA1 = nkA1; vA0 = nvA0; vA1 = nvA1;
    kB0 = nkB0; kB1 = nkB1; vB0 = nvB0; vB1 = nvB1;
    sA1 = sA2; sB1 = sB2;
  }

  // ---- combine the wave's 4 lane-groups via shfl (dims align lane-wise) ----
#pragma unroll
  for (int o = 16; o <= 32; o <<= 1) {
#pragma unroll
    for (int g = 0; g < G_; ++g) {
      const float mo = __shfl_xor(m[g], o, 64);
      const float lo = __shfl_xor(l[g], o, 64);
      float4 ao, bo;
      ao.x = __shfl_xor(aa[g].x, o, 64); ao.y = __shfl_xor(aa[g].y, o, 64);
      ao.z = __shfl_xor(aa[g].z, o, 64); ao.w = __shfl_xor(aa[g].w, o, 64);
      bo.x = __shfl_xor(ab[g].x, o, 64); bo.y = __shfl_xor(ab[g].y, o, 64);
      bo.z = __shfl_xor(ab[g].z, o, 64); bo.w = __shfl_xor(ab[g].w, o, 64);
      const float M = fmaxf(m[g], mo);
      const bool dead = (M == -INFINITY);
      const float c1 = dead ? 0.f : __expf(m[g] - M);
      const float c2 = dead ? 0.f : __expf(mo - M);
      l[g] = l[g] * c1 + lo * c2;
      aa[g].x = aa[g].x * c1 + ao.x * c2; aa[g].y = aa[g].y * c1 + ao.y * c2;
      aa[g].z = aa[g].z * c1 + ao.z * c2; aa[g].w = aa[g].w * c1 + ao.w * c2;
      ab[g].x = ab[g].x * c1 + bo.x * c2; ab[g].y = ab[g].y * c1 + bo.y * c2;
      ab[g].z = ab[g].z * c1 + bo.z * c2; ab[g].w = ab[g].w * c1 + bo.w * c2;
      m[g] = M;
    }
  }

  // ---- combine 4 waves via LDS ----
  __shared__ float sm_[4][G_];
  __shared__ float sl_[4][G_];
  __shared__ float sa_[4][G_][16][8];   // 8 KB
  if (grp == 0) {
#pragma unroll
    for (int g = 0; g < G_; ++g) {
      *(float4*)&sa_[wid][g][sub][0] = aa[g];
      *(float4*)&sa_[wid][g][sub][4] = ab[g];
    }
    if (sub == 0) {
#pragma unroll
      for (int g = 0; g < G_; ++g) { sm_[wid][g] = m[g]; sl_[wid][g] = l[g]; }
    }
  }
  __syncthreads();

  // wave wid finalizes head g=wid; lane covers dims 2*lane, 2*lane+1
  const int g = wid;
  const float M = fmaxf(fmaxf(sm_[0][g], sm_[1][g]),
                        fmaxf(sm_[2][g], sm_[3][g]));
  const int si = lane >> 2;
  const int sj = (2 * lane) & 7;
  float L = 0.f, Ox = 0.f, Oy = 0.f;
#pragma unroll
  for (int w = 0; w < 4; ++w) {
    const float c = __expf(sm_[w][g] - M);   // empty wave: exp(-inf)=0
    L += sl_[w][g] * c;
    Ox += sa_[w][g][si][sj] * c;
    Oy += sa_[w][g][si][sj + 1] * c;
  }
  float* wp = ws + (((size_t)b * KVH_ + kvh) * NPART_ + part) * PSTRIDE_;
  *(float2*)(wp + g * D_ + 2 * lane) = make_float2(Ox, Oy);
  if (lane == 0) {
    wp[G_ * D_ + g] = M;
    wp[G_ * D_ + G_ + g] = L;
  }
}

__global__ __launch_bounds__(512) void pa_reduce(
    const float* __restrict__ ws,
    const int* __restrict__ ctx_lens,
    float* __restrict__ out)
{
  const int bk = blockIdx.x;
  const int b = bk / KVH_;
  const int kvh = bk % KVH_;
  const int g = threadIdx.x >> 7;     // 0..3
  const int d = threadIdx.x & 127;    // 0..127
  const int ctx = ctx_lens[b];
  int np = (ctx + PART_ - 1) / PART_;
  if (np > NPART_) np = NPART_;

  const float* base = ws + ((size_t)b * KVH_ + kvh) * NPART_ * PSTRIDE_;

  float M = -INFINITY;
  for (int p = 0; p < np; ++p)
    M = fmaxf(M, base[p * PSTRIDE_ + G_ * D_ + g]);

  float L = 0.f, O = 0.f;
  for (int p = 0; p < np; ++p) {
    const float mp = base[p * PSTRIDE_ + G_ * D_ + g];
    const float lp = base[p * PSTRIDE_ + G_ * D_ + G_ + g];
    const float c = __expf(mp - M);
    L += lp * c;
    O += base[p * PSTRIDE_ + g * D_ + d] * c;
  }
  out[((size_t)b * H_ + (size_t)(kvh * G_ + g)) * D_ + d] = O / L;
}

extern "C" void kernel_launch(void* const* d_in, const int* in_sizes, int n_in,
                              void* d_out, int out_size, void* d_ws, size_t ws_size,
                              hipStream_t stream) {
  const float* q     = (const float*)d_in[0];
  const float* kc    = (const float*)d_in[1];
  const float* vc    = (const float*)d_in[2];
  const int*   slots = (const int*)d_in[3];
  const int*   lens  = (const int*)d_in[4];
  float* out = (float*)d_out;
  float* ws  = (float*)d_ws;   // needs 16*8*16*520*4 B ~= 4.3 MB

  dim3 grid1(NPART_, KVH_, B_);
  pa_partial<<<grid1, 256, 0, stream>>>(q, kc, vc, slots, lens, ws);
  pa_reduce<<<B_ * KVH_, 512, 0, stream>>>(ws, lens, out);
}